// Round 4
// baseline (262.823 us; speedup 1.0000x reference)
//
#include <hip/hip_runtime.h>
#include <stdint.h>

#define NUM_ENTRIES 1000000
#define NUM_HINTS   32768
#define MAX_SUBSET  512
#define CHUNKS      5

// One wave (64 lanes) per hint. Lane handles 8 slots (stride 64).
// Input widths detected in-kernel (wave-uniform, ~free). Output is INT32
// parity (harness reads d_out as np.int32): low 32 bits of the XOR, which is
// width-independent since XOR commutes with truncation.
__global__ __launch_bounds__(256) void hint_xor_kernel(
    const void* __restrict__ entries_v,
    const void* __restrict__ indices_v,
    const void* __restrict__ mask_v,
    int* __restrict__ out)
{
    const int wave = threadIdx.x >> 6;
    const int lane = threadIdx.x & 63;
    const int hint = blockIdx.x * 4 + wave;

    // ---- layout detection: sample first 64 dwords of each array (wave-uniform
    // votes, FP probability <= 2^-64 per decision) ----
    const unsigned* ew = (const unsigned*)entries_v;
    const unsigned* iw = (const unsigned*)indices_v;
    const unsigned* mw = (const unsigned*)mask_v;
    const unsigned es = ew[lane];
    const unsigned is = iw[lane];
    const unsigned ms = mw[lane];
    const bool odd = (lane & 1) != 0;

    // entries int64 => odd (high) dwords < 2^30 (values < 2^62)
    const bool ent32 = __any(odd && (es & 0xC0000000u));
    // indices int64 => odd (high) dwords all zero (values < 1e6)
    const bool idx32 = __any(odd && (is != 0u));
    // mask bytes iff any dword outside {0,1,1.0f}; else 8-byte iff odd dwords all 0
    const bool m_bytes = __any((ms != 0u) && (ms != 1u) && (ms != 0x3f800000u));
    const bool m_odd_nz = __any(odd && (ms != 0u));
    const int  mstep = m_odd_nz ? 1 : 2;   // dword stride when mask is 4B/8B

    const int*            idx32p = (const int*)indices_v;
    const long long*      idx64p = (const long long*)indices_v;
    const unsigned char*  m8p    = (const unsigned char*)mask_v;
    const unsigned*       m32p   = (const unsigned*)mask_v;

    const size_t rowoff = (size_t)hint * MAX_SUBSET;

    unsigned long long a0 = 0, a1 = 0, a2 = 0, a3 = 0, a4 = 0;

    #pragma unroll
    for (int k = 0; k < 8; ++k) {
        const size_t s = rowoff + (size_t)(k * 64 + lane);

        long long idx;
        if (idx32) idx = (long long)idx32p[s];
        else       idx = idx64p[s];

        unsigned mv;
        if (m_bytes) mv = (unsigned)m8p[s];
        else         mv = m32p[s * mstep];

        // bounds guard: misdetection becomes a wrong answer, not a page fault
        const bool v = (mv != 0u) && ((unsigned long long)idx < (unsigned long long)NUM_ENTRIES);

        if (v) {
            if (ent32) {
                const unsigned* e = (const unsigned*)entries_v + (size_t)idx * CHUNKS;
                a0 ^= e[0]; a1 ^= e[1]; a2 ^= e[2]; a3 ^= e[3]; a4 ^= e[4];
            } else {
                const unsigned long long* e =
                    (const unsigned long long*)entries_v + (size_t)idx * CHUNKS;
                a0 ^= e[0]; a1 ^= e[1]; a2 ^= e[2]; a3 ^= e[3]; a4 ^= e[4];
            }
        }
    }

    // 64-lane XOR butterfly reduction
    #pragma unroll
    for (int off = 32; off >= 1; off >>= 1) {
        a0 ^= (unsigned long long)__shfl_xor((long long)a0, off, 64);
        a1 ^= (unsigned long long)__shfl_xor((long long)a1, off, 64);
        a2 ^= (unsigned long long)__shfl_xor((long long)a2, off, 64);
        a3 ^= (unsigned long long)__shfl_xor((long long)a3, off, 64);
        a4 ^= (unsigned long long)__shfl_xor((long long)a4, off, 64);
    }

    if (lane == 0) {
        // harness reads d_out as int32; low 32 bits of the XOR are
        // width-independent (XOR commutes with truncation)
        int* o = out + (size_t)hint * CHUNKS;
        o[0] = (int)(unsigned)a0;
        o[1] = (int)(unsigned)a1;
        o[2] = (int)(unsigned)a2;
        o[3] = (int)(unsigned)a3;
        o[4] = (int)(unsigned)a4;
    }
}

extern "C" void kernel_launch(void* const* d_in, const int* in_sizes, int n_in,
                              void* d_out, int out_size, void* d_ws, size_t ws_size,
                              hipStream_t stream) {
    const void* entries = d_in[0];
    const void* indices = d_in[1];
    const void* mask    = d_in[2];
    int*        out     = (int*)d_out;

    // 4 waves/block, one wave per hint -> 32768/4 = 8192 blocks
    hint_xor_kernel<<<NUM_HINTS / 4, 256, 0, stream>>>(entries, indices, mask, out);
}